// Round 1
// baseline (3183.640 us; speedup 1.0000x reference)
//
#include <hip/hip_runtime.h>
#include <cstdint>

#define NPAT 8192
#define NBITS 4096

// ws layout:
//   [0, 4 MiB)        : packed sign bits B[i][w], uint32, i in [0,4096), w in [0,256)
//                       bit r of B[i*256+w] = signbit(W[(32w+r)*4096 + i])
//   [4 MiB, +32 KiB)  : h0 float[8192] (exact integers)

__global__ void pack_kernel(const float* __restrict__ W, uint32_t* __restrict__ B) {
    // grid: 4096 blocks of 256 threads; blockIdx.x = (iblk<<8) | w
    int w = blockIdx.x & 255;
    int i = (blockIdx.x >> 8) * 256 + threadIdx.x;
    uint32_t word = 0;
    const float* base = W + (size_t)(w * 32) * NBITS + i;
    #pragma unroll
    for (int r = 0; r < 32; ++r) {
        float v = base[(size_t)r * NBITS];       // coalesced: 256 consecutive floats per r
        word |= (__float_as_uint(v) >> 31) << r;
    }
    B[(size_t)i * 256 + w] = word;
}

__global__ void gemv_kernel(const float* __restrict__ W, const float* __restrict__ state,
                            float* __restrict__ h0) {
    // 2048 blocks x 256 threads; one wave per row. Exact in f32 (|partials| <= 4096 < 2^24).
    int wid = threadIdx.x >> 6, lane = threadIdx.x & 63;
    int p = blockIdx.x * 4 + wid;
    const float* row = W + (size_t)p * NBITS;
    float acc = 0.f;
    for (int k = lane; k < NBITS; k += 64) acc += row[k] * state[k];
    #pragma unroll
    for (int d = 1; d < 64; d <<= 1) acc += __shfl_xor(acc, d, 64);
    if (lane == 0) h0[p] = acc;
}

// Single-workgroup sequential sweep. 512 threads = 64 blocks-of-128 x 8 accumulators,
// reproducing numpy pairwise_sum(f32) bit-exactly:
//   r_j = (((a[j] + a[j+8]) + a[j+16]) + ... )  (16 sequential adds, k ascending)
//   block: ((r0+r1)+(r2+r3))+((r4+r5)+(r6+r7))  -> shfl_xor 1,2,4
//   64 block sums: perfect adjacent-pair tree   -> shfl_xor 8,16,32 + LDS tree over 8 waves
__launch_bounds__(512, 1)
__global__ void seq_kernel(const uint32_t* __restrict__ Bw, const float* __restrict__ h0,
                           const float* __restrict__ state, const int* __restrict__ perm,
                           float* __restrict__ out) {
    __shared__ float part[8];
    __shared__ int flag;
    const int t = threadIdx.x;
    const int b = t >> 3, j = t & 7;          // block-of-128 index, accumulator index
    const int lane = t & 63, wid = t >> 6;

    float h[16], hn[16];
    #pragma unroll
    for (int k = 0; k < 16; ++k) h[k] = h0[128 * b + j + 8 * k];

    const uint4* B4 = (const uint4*)Bw;       // 64 uint4 per column; thread uses element b
    float prev = 0.f;                          // live only in thread 0

    int   i_next  = perm[0];
    uint4 cw_next = B4[(size_t)i_next * 64 + b];
    float vi_next = state[i_next];

    for (int step = -1; step < NBITS; ++step) {
        int   i  = i_next;
        uint4 cw = cw_next;
        float vi = vi_next;
        float m  = -2.0f * vi;                 // h_new = h + m*c, c = +/-1 from sign bit

        // prefetch next column while this step computes (perm known in advance)
        int pf = step + 1;
        if (pf < NBITS) {
            i_next  = perm[pf];
            cw_next = B4[(size_t)i_next * 64 + b];
            vi_next = state[i_next];
        }

        float r;
        if (step >= 0) {
            #pragma unroll
            for (int k = 0; k < 16; ++k) {
                uint32_t word = (&cw.x)[k >> 2];
                int pos = j + 8 * (k & 3);                     // p = 128b + j + 8k
                uint32_t sgn = (word << (31 - pos)) & 0x80000000u;
                float delta = __uint_as_float(__float_as_uint(m) ^ sgn); // m * c, exact
                float v = h[k] + delta;                        // exact integer math in f32
                hn[k] = v;
                float a = fmaxf(v, 0.0f);
                r = (k == 0) ? a * a : fmaf(a, a, r);          // a*a exact; fma == add of exact square
            }
        } else {
            // initial energy of h0, same summation structure
            #pragma unroll
            for (int k = 0; k < 16; ++k) {
                float a = fmaxf(h[k], 0.0f);
                r = (k == 0) ? a * a : fmaf(a, a, r);
            }
        }

        // np-exact reduction: 8 accumulators -> block sums -> adjacent-pair tree
        r += __shfl_xor(r, 1, 64);
        r += __shfl_xor(r, 2, 64);
        r += __shfl_xor(r, 4, 64);
        r += __shfl_xor(r, 8, 64);
        r += __shfl_xor(r, 16, 64);
        r += __shfl_xor(r, 32, 64);
        if (lane == 0) part[wid] = r;
        __syncthreads();
        if (t == 0) {
            float v = ((part[0] + part[1]) + (part[2] + part[3]))
                    + ((part[4] + part[5]) + (part[6] + part[7]));
            float E = -v;
            if (step < 0) {
                prev = E;
                flag = 0;
            } else {
                int acc = (E < prev) ? 1 : 0;
                if (acc) prev = E;
                flag = acc;
                out[i] = acc ? -vi : vi;       // each i visited exactly once
            }
        }
        __syncthreads();
        if (step >= 0 && flag) {
            #pragma unroll
            for (int k = 0; k < 16; ++k) h[k] = hn[k];
        }
    }
}

extern "C" void kernel_launch(void* const* d_in, const int* in_sizes, int n_in,
                              void* d_out, int out_size, void* d_ws, size_t ws_size,
                              hipStream_t stream) {
    const float* W     = (const float*)d_in[0];
    const float* state = (const float*)d_in[1];
    const int*   perm  = (const int*)d_in[2];
    float*       out   = (float*)d_out;

    uint32_t* B  = (uint32_t*)d_ws;
    float*    h0 = (float*)((char*)d_ws + (size_t)4096 * 256 * 4);

    pack_kernel<<<4096, 256, 0, stream>>>(W, B);
    gemv_kernel<<<2048, 256, 0, stream>>>(W, state, h0);
    seq_kernel<<<1, 512, 0, stream>>>(B, h0, state, perm, out);
}

// Round 2
// 3056.210 us; speedup vs baseline: 1.0417x; 1.0417x over previous
//
#include <hip/hip_runtime.h>
#include <cstdint>

#define NPAT 8192
#define NBITS 4096

// ws layout:
//   [0, 4 MiB)        : packed sign bits B[i][w], uint32, i in [0,4096), w in [0,256)
//                       bit r of B[i*256+w] = signbit(W[(32w+r)*4096 + i])
//   [4 MiB, +32 KiB)  : h0 float[8192] (exact integers)

__global__ void pack_kernel(const float* __restrict__ W, uint32_t* __restrict__ B) {
    int w = blockIdx.x & 255;
    int i = (blockIdx.x >> 8) * 256 + threadIdx.x;
    uint32_t word = 0;
    const float* base = W + (size_t)(w * 32) * NBITS + i;
    #pragma unroll
    for (int r = 0; r < 32; ++r) {
        float v = base[(size_t)r * NBITS];       // coalesced
        word |= (__float_as_uint(v) >> 31) << r;
    }
    B[(size_t)i * 256 + w] = word;
}

__global__ void gemv_kernel(const float* __restrict__ W, const float* __restrict__ state,
                            float* __restrict__ h0) {
    // one wave per row; exact in f32 (|partials| <= 4096 < 2^24, any association exact)
    int wid = threadIdx.x >> 6, lane = threadIdx.x & 63;
    int p = blockIdx.x * 4 + wid;
    const float* row = W + (size_t)p * NBITS;
    float acc = 0.f;
    for (int k = lane; k < NBITS; k += 64) acc += row[k] * state[k];
    #pragma unroll
    for (int d = 1; d < 64; d <<= 1) acc += __shfl_xor(acc, d, 64);
    if (lane == 0) h0[p] = acc;
}

// Single-workgroup sequential sweep, numpy-pairwise-exact energy:
//   thread t: block b = t>>3 (of 64 blocks of 128), accumulator j = t&7
//   r_j = 16 sequential adds of exact squares (fma of exact a*a == add)
//   shfl_xor 1,2,4 : ((r0+r1)+(r2+r3))+((r4+r5)+(r6+r7))  per block
//   shfl_xor 8,16,32 + 8-part LDS tree : perfect adjacent-pair tree over 64 blocks
// One lgkm-only barrier per step (column prefetches stay in flight across it).
__launch_bounds__(512, 1)
__global__ void seq_kernel(const uint32_t* __restrict__ Bw, const float* __restrict__ h0,
                           const float* __restrict__ state, const int* __restrict__ perm,
                           float* __restrict__ out) {
    __shared__ float part[2][8];
    __shared__ int   perm_s[NBITS];
    __shared__ float vals_s[NBITS];

    const int t = threadIdx.x;
    const int b = t >> 3, j = t & 7;
    const int lane = t & 63, wid = t >> 6;

    // preload perm + gathered state values into LDS
    for (int q = t; q < NBITS; q += 512) {
        int ii = perm[q];
        perm_s[q] = ii;
        vals_s[q] = state[ii];
    }

    float h[16], v[16], d[16];
    #pragma unroll
    for (int k = 0; k < 16; ++k) h[k] = h0[128 * b + j + 8 * k];

    __syncthreads();   // once, before the loop — full drain is fine here

    const uint4* B4 = (const uint4*)Bw;   // 64 uint4 per column; this thread uses elem b

    // depth-3 column prefetch pipeline + col 0 for step 0's deltas
    uint4 c0 = B4[(size_t)perm_s[0] * 64 + b];
    uint4 q0 = B4[(size_t)perm_s[1] * 64 + b];
    uint4 q1 = B4[(size_t)perm_s[2] * 64 + b];
    uint4 q2 = B4[(size_t)perm_s[3] * 64 + b];

    float prev;

    // ---- step -1: initial energy of h0, and deltas for step 0
    {
        float r;
        #pragma unroll
        for (int k = 0; k < 16; ++k) {
            float a = fmaxf(h[k], 0.0f);
            r = (k == 0) ? a * a : fmaf(a, a, r);
        }
        float m = -2.0f * vals_s[0];
        #pragma unroll
        for (int k = 0; k < 16; ++k) {
            uint32_t word = (&c0.x)[k >> 2];
            int pos = j + 8 * (k & 3);
            uint32_t sgn = (word << (31 - pos)) & 0x80000000u;
            d[k] = __uint_as_float(__float_as_uint(m) ^ sgn);   // -2*vi*c, exact
        }
        r += __shfl_xor(r, 1, 64);
        r += __shfl_xor(r, 2, 64);
        r += __shfl_xor(r, 4, 64);
        r += __shfl_xor(r, 8, 64);
        r += __shfl_xor(r, 16, 64);
        r += __shfl_xor(r, 32, 64);
        if (lane == 0) part[0][wid] = r;
        asm volatile("s_waitcnt lgkmcnt(0)\n\ts_barrier" ::: "memory");
        const float4* pp = (const float4*)&part[0][0];
        float4 pa = pp[0], pb = pp[1];
        prev = -(((pa.x + pa.y) + (pa.z + pa.w)) + ((pb.x + pb.y) + (pb.z + pb.w)));
    }

    for (int s = 0; s < NBITS; ++s) {
        const int buf = 1 - (s & 1);                 // step -1 used part[0]
        const int sn1 = (s + 1 < NBITS) ? s + 1 : NBITS - 1;
        const int sn4 = (s + 4 < NBITS) ? s + 4 : NBITS - 1;

        int   is  = perm_s[s];                       // uniform LDS broadcasts
        float vis = vals_s[s];
        float vin = vals_s[sn1];
        int   ipf = perm_s[sn4];
        uint4 qn  = B4[(size_t)ipf * 64 + b];        // prefetch col for step s+3

        // proposed h and numpy-exact per-accumulator chain
        float r;
        #pragma unroll
        for (int k = 0; k < 16; ++k) {
            float vv = h[k] + d[k];                  // exact integer math in f32
            v[k] = vv;
            float a = fmaxf(vv, 0.0f);
            r = (k == 0) ? a * a : fmaf(a, a, r);
        }

        // next step's deltas (accept-independent) — overlaps the reduction wait
        float m = -2.0f * vin;
        #pragma unroll
        for (int k = 0; k < 16; ++k) {
            uint32_t word = (&q0.x)[k >> 2];
            int pos = j + 8 * (k & 3);
            uint32_t sgn = (word << (31 - pos)) & 0x80000000u;
            d[k] = __uint_as_float(__float_as_uint(m) ^ sgn);
        }

        r += __shfl_xor(r, 1, 64);
        r += __shfl_xor(r, 2, 64);
        r += __shfl_xor(r, 4, 64);
        r += __shfl_xor(r, 8, 64);
        r += __shfl_xor(r, 16, 64);
        r += __shfl_xor(r, 32, 64);
        if (lane == 0) part[buf][wid] = r;
        asm volatile("s_waitcnt lgkmcnt(0)\n\ts_barrier" ::: "memory");
        const float4* pp = (const float4*)&part[buf][0];
        float4 pa = pp[0], pb = pp[1];
        float E = -(((pa.x + pa.y) + (pa.z + pa.w)) + ((pb.x + pb.y) + (pb.z + pb.w)));

        // every thread decides redundantly — no flag round-trip, no 2nd barrier
        bool acc = E < prev;
        if (acc) prev = E;
        if (t == 0) out[is] = acc ? -vis : vis;      // each i visited exactly once
        #pragma unroll
        for (int k = 0; k < 16; ++k) h[k] = acc ? v[k] : h[k];

        q0 = q1; q1 = q2; q2 = qn;
    }
}

extern "C" void kernel_launch(void* const* d_in, const int* in_sizes, int n_in,
                              void* d_out, int out_size, void* d_ws, size_t ws_size,
                              hipStream_t stream) {
    const float* W     = (const float*)d_in[0];
    const float* state = (const float*)d_in[1];
    const int*   perm  = (const int*)d_in[2];
    float*       out   = (float*)d_out;

    uint32_t* B  = (uint32_t*)d_ws;
    float*    h0 = (float*)((char*)d_ws + (size_t)4096 * 256 * 4);

    pack_kernel<<<4096, 256, 0, stream>>>(W, B);
    gemv_kernel<<<2048, 256, 0, stream>>>(W, state, h0);
    seq_kernel<<<1, 512, 0, stream>>>(B, h0, state, perm, out);
}

// Round 3
// 2742.648 us; speedup vs baseline: 1.1608x; 1.1143x over previous
//
#include <hip/hip_runtime.h>
#include <cstdint>

#define NPAT 8192
#define NBITS 4096

// ws layout:
//   [0, 4 MiB)      : Bt[i][t] delta-sign bits, uint32, i in [0,4096), t in [0,256)
//                     thread t: b = t>>2, a = t&3
//                     bit k     (k=0..15): sign of d for element p = 128b + 2a     + 8k
//                     bit 16+k           : sign of d for element p = 128b + 2a + 1 + 8k
//                     where d = -2*state[i]*W[p][i]  (always +/-2.0; state = ORIGINAL
//                     state, valid because perm visits each i exactly once)
//   [4 MiB, +32 KiB): h0 float[8192] (exact integers)

__global__ void pack_kernel(const float* __restrict__ W, const float* __restrict__ state,
                            uint32_t* __restrict__ Bt) {
    int b = blockIdx.x & 63;                         // block-of-128 rows
    int i = (blockIdx.x >> 6) * 256 + threadIdx.x;   // column
    // signbit(-2*state[i]*W) = signW ^ signV ^ 1
    uint32_t spre = (__float_as_uint(state[i]) >> 31) ^ 1u;
    uint32_t wd0 = 0, wd1 = 0, wd2 = 0, wd3 = 0;
    const float* base = W + (size_t)(128 * b) * NBITS + i;
    #pragma unroll
    for (int q = 0; q < 128; ++q) {
        uint32_t bit = (__float_as_uint(base[(size_t)q * NBITS]) >> 31) ^ spre;  // coalesced
        int j = q & 7, k = q >> 3;
        int a = j >> 1, hi = j & 1;
        uint32_t add = bit << (16 * hi + k);
        if (a == 0) wd0 |= add;
        else if (a == 1) wd1 |= add;
        else if (a == 2) wd2 |= add;
        else wd3 |= add;
    }
    *(uint4*)(Bt + (size_t)i * 256 + 4 * b) = make_uint4(wd0, wd1, wd2, wd3);
}

__global__ void gemv_kernel(const float* __restrict__ W, const float* __restrict__ state,
                            float* __restrict__ h0) {
    // one wave per row; exact in f32 (|partials| <= 4096 < 2^24, any association exact)
    int wid = threadIdx.x >> 6, lane = threadIdx.x & 63;
    int p = blockIdx.x * 4 + wid;
    const float* row = W + (size_t)p * NBITS;
    float acc = 0.f;
    for (int k = lane; k < NBITS; k += 64) acc += row[k] * state[k];
    #pragma unroll
    for (int d = 1; d < 64; d <<= 1) acc += __shfl_xor(acc, d, 64);
    if (lane == 0) h0[p] = acc;
}

// VALU-only intra-wave reduction of the numpy pairwise tree.
// Input s1 = (r_{2a} + r_{2a+1}) for this thread; block = 4 lanes (quad).
// Stages (each bit-exact vs numpy's adjacent-pair tree by add-commutativity):
//  quad_perm[1,0,3,2] : (s0+s1),(s2+s3)    quad_perm[2,3,0,1] : block sum
//  row_half_mirror    : blocks b^1          row_mirror        : blocks b^2
//  ds_swizzle xor16   : blocks b^4          permlane32_swap   : blocks b^8 -> wave sum
__device__ __forceinline__ float tree_reduce(float s1) {
    float x = s1;
    x = __uint_as_float(__builtin_amdgcn_update_dpp(__float_as_uint(x), __float_as_uint(x),
                                                    0xB1, 0xf, 0xf, false)) + x;   // quad_perm [1,0,3,2]
    x = __uint_as_float(__builtin_amdgcn_update_dpp(__float_as_uint(x), __float_as_uint(x),
                                                    0x4E, 0xf, 0xf, false)) + x;   // quad_perm [2,3,0,1]
    x = __uint_as_float(__builtin_amdgcn_update_dpp(__float_as_uint(x), __float_as_uint(x),
                                                    0x141, 0xf, 0xf, false)) + x;  // row_half_mirror
    x = __uint_as_float(__builtin_amdgcn_update_dpp(__float_as_uint(x), __float_as_uint(x),
                                                    0x140, 0xf, 0xf, false)) + x;  // row_mirror
    x = __int_as_float(__builtin_amdgcn_ds_swizzle(__float_as_int(x), 0x401F)) + x; // lane ^ 16
#if __has_builtin(__builtin_amdgcn_permlane32_swap)
    {
        auto pr = __builtin_amdgcn_permlane32_swap(__float_as_uint(x), __float_as_uint(x),
                                                   false, false);
        x = __uint_as_float(pr[0]) + __uint_as_float(pr[1]);                        // lane ^ 32
    }
#else
    x += __shfl_xor(x, 32, 64);
#endif
    return x;
}

__launch_bounds__(256, 1)
__global__ void seq_kernel(const uint32_t* __restrict__ Bt, const float* __restrict__ h0,
                           const float* __restrict__ state, const int* __restrict__ perm,
                           float* __restrict__ out) {
    __shared__ int   perm_s[NBITS];
    __shared__ float vals_s[NBITS];
    __shared__ alignas(16) float part[2][4];

    const int t = threadIdx.x;
    const int b = t >> 2, a = t & 3;
    const int lane = t & 63, wid = t >> 6;

    for (int q = t; q < NBITS; q += 256) {
        int ii = perm[q];
        perm_s[q] = ii;
        vals_s[q] = state[ii];
    }

    float hl[16], hh[16], dl[16], dh[16];
    #pragma unroll
    for (int k = 0; k < 16; ++k) {
        float2 p2 = *(const float2*)(h0 + 128 * b + 2 * a + 8 * k);  // 8B aligned
        hl[k] = p2.x; hh[k] = p2.y;
    }

    __syncthreads();   // LDS tables + h ready; full drain fine (once)

    // word prefetch pipeline, depth 4
    uint32_t w0 = Bt[(size_t)perm_s[0] * 256 + t];
    uint32_t w1 = Bt[(size_t)perm_s[1] * 256 + t];
    uint32_t w2 = Bt[(size_t)perm_s[2] * 256 + t];
    uint32_t w3 = Bt[(size_t)perm_s[3] * 256 + t];

    float Sprev;
    {   // S0 = sum(relu(h0)^2), numpy-pairwise-exact
        float rl, rh;
        #pragma unroll
        for (int k = 0; k < 16; ++k) {
            float a1 = fmaxf(hl[k], 0.0f);
            float a2 = fmaxf(hh[k], 0.0f);
            rl = (k == 0) ? a1 * a1 : fmaf(a1, a1, rl);
            rh = (k == 0) ? a2 * a2 : fmaf(a2, a2, rh);
        }
        float red = tree_reduce(rl + rh);
        if (lane == 0) part[0][wid] = red;
        asm volatile("s_waitcnt lgkmcnt(0)\n\ts_barrier" ::: "memory");
        float4 p4 = *reinterpret_cast<const float4*>(&part[0][0]);
        Sprev = (p4.x + p4.y) + (p4.z + p4.w);
    }

    for (int s = 0; s < NBITS; ++s) {
        const int buf = 1 - (s & 1);                   // step -1 used part[0]
        const int sn  = (s + 4 < NBITS) ? s + 4 : NBITS - 1;
        int   is  = perm_s[s];                         // uniform LDS broadcasts
        float vis = vals_s[s];
        uint32_t wn = Bt[(size_t)perm_s[sn] * 256 + t];  // prefetch (stays in flight)

        // delta gen: 2 VALU/elem (shift + and_or), d = +/-2.0 exactly
        #pragma unroll
        for (int k = 0; k < 16; ++k) {
            dl[k] = __uint_as_float(((w0 << (31 - k)) & 0x80000000u) | 0x40000000u);
            dh[k] = __uint_as_float(((w0 << (15 - k)) & 0x80000000u) | 0x40000000u);
        }

        // proposed-h relu^2 chains (numpy accumulator order, k ascending; all exact)
        float rl, rh;
        #pragma unroll
        for (int k = 0; k < 16; ++k) {
            float vlo = hl[k] + dl[k];
            float vhi = hh[k] + dh[k];
            float a1 = fmaxf(vlo, 0.0f);
            float a2 = fmaxf(vhi, 0.0f);
            rl = (k == 0) ? a1 * a1 : fmaf(a1, a1, rl);
            rh = (k == 0) ? a2 * a2 : fmaf(a2, a2, rh);
        }

        float red = tree_reduce(rl + rh);
        if (lane == 0) part[buf][wid] = red;
        asm volatile("s_waitcnt lgkmcnt(0)\n\ts_barrier" ::: "memory");
        float4 p4 = *reinterpret_cast<const float4*>(&part[buf][0]);
        float S = (p4.x + p4.y) + (p4.z + p4.w);

        // accept iff E_new < E_prev  <=>  S_new > S_prev (exact; ties reject)
        bool acc = S > Sprev;
        if (acc) Sprev = S;
        float af = acc ? 1.0f : 0.0f;
        if (t == 0) out[is] = acc ? -vis : vis;        // each i visited exactly once

        // h += acc ? d : 0   (fma exact: d*1=d, d*0=+/-0, adds exact integers)
        #pragma unroll
        for (int k = 0; k < 16; ++k) {
            hl[k] = fmaf(dl[k], af, hl[k]);
            hh[k] = fmaf(dh[k], af, hh[k]);
        }

        w0 = w1; w1 = w2; w2 = w3; w3 = wn;
    }
}

extern "C" void kernel_launch(void* const* d_in, const int* in_sizes, int n_in,
                              void* d_out, int out_size, void* d_ws, size_t ws_size,
                              hipStream_t stream) {
    const float* W     = (const float*)d_in[0];
    const float* state = (const float*)d_in[1];
    const int*   perm  = (const int*)d_in[2];
    float*       out   = (float*)d_out;

    uint32_t* Bt = (uint32_t*)d_ws;
    float*    h0 = (float*)((char*)d_ws + (size_t)4096 * 256 * 4);

    pack_kernel<<<1024, 256, 0, stream>>>(W, state, Bt);
    gemv_kernel<<<2048, 256, 0, stream>>>(W, state, h0);
    seq_kernel<<<1, 256, 0, stream>>>(Bt, h0, state, perm, out);
}

// Round 4
// 2238.215 us; speedup vs baseline: 1.4224x; 1.2254x over previous
//
#include <hip/hip_runtime.h>
#include <cstdint>

#define NPAT 8192
#define NBITS 4096

typedef float f32x2 __attribute__((ext_vector_type(2)));

// ws layout:
//   [0, 4 MiB)      : Bt[i][t] delta-sign bits, uint32, i in [0,4096), t in [0,256)
//                     thread t: b = t>>2, a = t&3
//                     bit k     (k=0..15): sign of d for element p = 128b + 2a     + 8k
//                     bit 16+k           : sign of d for element p = 128b + 2a + 1 + 8k
//                     where d = -2*state[i]*W[p][i] (state = ORIGINAL state; valid
//                     because perm visits each i exactly once)
//   [4 MiB, +32 KiB): h0 float[8192] (exact integers)

__global__ void pack_kernel(const float* __restrict__ W, const float* __restrict__ state,
                            uint32_t* __restrict__ Bt) {
    int b = blockIdx.x & 63;
    int i = (blockIdx.x >> 6) * 256 + threadIdx.x;
    uint32_t spre = (__float_as_uint(state[i]) >> 31) ^ 1u;
    uint32_t wd0 = 0, wd1 = 0, wd2 = 0, wd3 = 0;
    const float* base = W + (size_t)(128 * b) * NBITS + i;
    #pragma unroll
    for (int q = 0; q < 128; ++q) {
        uint32_t bit = (__float_as_uint(base[(size_t)q * NBITS]) >> 31) ^ spre;  // coalesced
        int j = q & 7, k = q >> 3;
        int a = j >> 1, hi = j & 1;
        uint32_t add = bit << (16 * hi + k);
        if (a == 0) wd0 |= add;
        else if (a == 1) wd1 |= add;
        else if (a == 2) wd2 |= add;
        else wd3 |= add;
    }
    *(uint4*)(Bt + (size_t)i * 256 + 4 * b) = make_uint4(wd0, wd1, wd2, wd3);
}

__global__ void gemv_kernel(const float* __restrict__ W, const float* __restrict__ state,
                            float* __restrict__ h0) {
    int wid = threadIdx.x >> 6, lane = threadIdx.x & 63;
    int p = blockIdx.x * 4 + wid;
    const float* row = W + (size_t)p * NBITS;
    float acc = 0.f;
    for (int k = lane; k < NBITS; k += 64) acc += row[k] * state[k];
    #pragma unroll
    for (int d = 1; d < 64; d <<= 1) acc += __shfl_xor(acc, d, 64);
    if (lane == 0) h0[p] = acc;
}

__device__ __forceinline__ f32x2 pk_add(f32x2 a, f32x2 b) {
    f32x2 d;
    asm("v_pk_add_f32 %0, %1, %2" : "=v"(d) : "v"(a), "v"(b));
    return d;
}
__device__ __forceinline__ f32x2 pk_mul(f32x2 a, f32x2 b) {
    f32x2 d;
    asm("v_pk_mul_f32 %0, %1, %2" : "=v"(d) : "v"(a), "v"(b));
    return d;
}
__device__ __forceinline__ f32x2 pk_fma(f32x2 a, f32x2 b, f32x2 c) {
    f32x2 d;
    asm("v_pk_fma_f32 %0, %1, %2, %3" : "=v"(d) : "v"(a), "v"(b), "v"(c));
    return d;
}

// Exact numpy-pairwise tree (mapping proven in R3). All-VALU when permlane
// builtins exist; every stage pairs value(g) with value(g^2^s) bit-exactly.
__device__ __forceinline__ float tree_reduce(float x) {
    x = __uint_as_float(__builtin_amdgcn_update_dpp(__float_as_uint(x), __float_as_uint(x),
                                                    0xB1, 0xf, 0xf, false)) + x;   // quad xor1
    x = __uint_as_float(__builtin_amdgcn_update_dpp(__float_as_uint(x), __float_as_uint(x),
                                                    0x4E, 0xf, 0xf, false)) + x;   // quad xor2
    x = __uint_as_float(__builtin_amdgcn_update_dpp(__float_as_uint(x), __float_as_uint(x),
                                                    0x141, 0xf, 0xf, false)) + x;  // quads q^1
    x = __uint_as_float(__builtin_amdgcn_update_dpp(__float_as_uint(x), __float_as_uint(x),
                                                    0x140, 0xf, 0xf, false)) + x;  // q^3 == q^2 (invariant)
#if __has_builtin(__builtin_amdgcn_permlane16_swap)
    {
        auto pr = __builtin_amdgcn_permlane16_swap(__float_as_uint(x), __float_as_uint(x),
                                                   false, false);
        x = __uint_as_float(pr[0]) + __uint_as_float(pr[1]);                        // lane^16
    }
#else
    x = __int_as_float(__builtin_amdgcn_ds_swizzle(__float_as_int(x), 0x401F)) + x; // lane^16
#endif
#if __has_builtin(__builtin_amdgcn_permlane32_swap)
    {
        auto pr = __builtin_amdgcn_permlane32_swap(__float_as_uint(x), __float_as_uint(x),
                                                   false, false);
        x = __uint_as_float(pr[0]) + __uint_as_float(pr[1]);                        // lane^32
    }
#else
    x += __shfl_xor(x, 32, 64);
#endif
    return x;
}

__launch_bounds__(256, 1)
__global__ void seq_kernel(const uint32_t* __restrict__ Bt, const float* __restrict__ h0,
                           const float* __restrict__ state, const int* __restrict__ perm,
                           float* __restrict__ out) {
    __shared__ alignas(16) float part[2][4];
    __shared__ int2 pv[NBITS];                 // (i, bits(state[i])) per visit order

    const int t = threadIdx.x;
    const int b = t >> 2, a = t & 3;
    const int lane = t & 63, wid = t >> 6;

    for (int q = t; q < NBITS; q += 256) {
        int ii = perm[q];
        pv[q] = make_int2(ii, __float_as_int(state[ii]));
    }

    f32x2 h[16];
    #pragma unroll
    for (int k = 0; k < 16; ++k) h[k] = *(const f32x2*)(h0 + 128 * b + 2 * a + 8 * k);

    __syncthreads();

    // ---- prologue pipelines ----
    int2 q0 = pv[0], q1 = pv[1], q2 = pv[2], q3 = pv[3], q4 = pv[4], q5 = pv[5];
    uint32_t wd0 = Bt[(size_t)q0.x * 256 + t];     // word(step 0)
    uint32_t wq[4];
    wq[1] = Bt[(size_t)q1.x * 256 + t];            // word(1)
    wq[2] = Bt[(size_t)q2.x * 256 + t];            // word(2)
    wq[3] = Bt[(size_t)q3.x * 256 + t];            // word(3)
    wq[0] = Bt[(size_t)q4.x * 256 + t];            // word(4)
    int2 pvB = q5;                                  // i_{s+5} carrier
    int2 pva[2];
    pva[0] = q0;                                    // (i_0, vi_0)

    f32x2 dq[2][16];
    #pragma unroll
    for (int k = 0; k < 16; ++k) {                  // d_0 from word(0)
        uint32_t lo = ((wd0 << (31 - k)) & 0x80000000u) | 0x40000000u;
        uint32_t hi = ((wd0 << (15 - k)) & 0x80000000u) | 0x40000000u;
        dq[0][k] = (f32x2){__uint_as_float(lo), __uint_as_float(hi)};
    }

    float Sprev;
    {   // S(h_0), numpy-exact
        f32x2 r;
        #pragma unroll
        for (int k = 0; k < 16; ++k) {
            f32x2 x = h[k];
            x.x = fmaxf(x.x, 0.f);
            x.y = fmaxf(x.y, 0.f);
            r = (k == 0) ? pk_mul(x, x) : pk_fma(x, x, r);
        }
        float red = tree_reduce(r.x + r.y);
        if (lane == 0) part[1][wid] = red;
        asm volatile("s_waitcnt lgkmcnt(0)\n\ts_barrier" ::: "memory");
        float4 pS = *(const float4*)(&part[1][0]);
        Sprev = (pS.x + pS.y) + (pS.z + pS.w);
    }

    for (int sb = 0; sb < NBITS; sb += 4) {
        #pragma unroll
        for (int u = 0; u < 4; ++u) {
            const int s = sb + u;

            // phase 1: proposed-h relu^2 chains (packed; bit-exact numpy order)
            f32x2 r;
            #pragma unroll
            for (int k = 0; k < 16; ++k) {
                f32x2 vv = pk_add(h[k], dq[u & 1][k]);
                vv.x = fmaxf(vv.x, 0.f);
                vv.y = fmaxf(vv.y, 0.f);
                r = (k == 0) ? pk_mul(vv, vv) : pk_fma(vv, vv, r);
            }
            float red = tree_reduce(r.x + r.y);
            if (lane == 0) part[u & 1][wid] = red;
            asm volatile("s_waitcnt lgkmcnt(0)\n\ts_barrier" ::: "memory");
            float4 pS = *(const float4*)(&part[u & 1][0]);   // issue early...

            // ...hide its latency under accept-independent work:
            uint32_t wNext = wq[(u + 1) & 3];                // word(s+1), loaded 4 steps ago
            #pragma unroll
            for (int k = 0; k < 16; ++k) {                   // d_{s+1}
                uint32_t lo = ((wNext << (31 - k)) & 0x80000000u) | 0x40000000u;
                uint32_t hi = ((wNext << (15 - k)) & 0x80000000u) | 0x40000000u;
                dq[(u + 1) & 1][k] = (f32x2){__uint_as_float(lo), __uint_as_float(hi)};
            }
            wq[(u + 1) & 3] = Bt[(size_t)pvB.x * 256 + t];   // word(s+5), consumed at s+4
            pvB = pv[(s + 6 < NBITS) ? s + 6 : NBITS - 1];
            pva[(u + 1) & 1] = pv[(s + 1 < NBITS) ? s + 1 : NBITS - 1];

            // decide (every thread redundantly; ties reject)
            float S = (pS.x + pS.y) + (pS.z + pS.w);
            bool acc = S > Sprev;
            Sprev = acc ? S : Sprev;
            f32x2 af2;
            af2.x = af2.y = acc ? 1.0f : 0.0f;
            int2 po = pva[u & 1];
            if (t == 0) {
                float vi = __int_as_float(po.y);
                out[po.x] = acc ? -vi : vi;                  // each i exactly once
            }
            // h += acc ? d : 0  (exact: d*1=d, d*0=+/-0)
            #pragma unroll
            for (int k = 0; k < 16; ++k) h[k] = pk_fma(dq[u & 1][k], af2, h[k]);
        }
    }
}

extern "C" void kernel_launch(void* const* d_in, const int* in_sizes, int n_in,
                              void* d_out, int out_size, void* d_ws, size_t ws_size,
                              hipStream_t stream) {
    const float* W     = (const float*)d_in[0];
    const float* state = (const float*)d_in[1];
    const int*   perm  = (const int*)d_in[2];
    float*       out   = (float*)d_out;

    uint32_t* Bt = (uint32_t*)d_ws;
    float*    h0 = (float*)((char*)d_ws + (size_t)4096 * 256 * 4);

    pack_kernel<<<1024, 256, 0, stream>>>(W, state, Bt);
    gemv_kernel<<<2048, 256, 0, stream>>>(W, state, h0);
    seq_kernel<<<1, 256, 0, stream>>>(Bt, h0, state, perm, out);
}

// Round 5
// 2088.179 us; speedup vs baseline: 1.5246x; 1.0719x over previous
//
#include <hip/hip_runtime.h>
#include <cstdint>

#define NPAT 8192
#define NBITS 4096

typedef float f32x2 __attribute__((ext_vector_type(2)));
typedef unsigned int u32;

// ws layout:
//   [0, 4 MiB)      : Bt[i][t] delta-sign bits, uint32, i in [0,4096), t in [0,256)
//                     thread t: b = t>>2, a = t&3
//                     bit k     (k=0..15): sign of d for element p = 128b + 2a     + 8k
//                     bit 16+k           : sign of d for element p = 128b + 2a + 1 + 8k
//                     where d = -2*state[i]*W[p][i] (state = ORIGINAL state; valid
//                     because perm visits each i exactly once)
//   [4 MiB, +32 KiB): h0 float[8192] (exact integers)

__global__ void pack_kernel(const float* __restrict__ W, const float* __restrict__ state,
                            uint32_t* __restrict__ Bt) {
    int b = blockIdx.x & 63;
    int i = (blockIdx.x >> 6) * 256 + threadIdx.x;
    uint32_t spre = (__float_as_uint(state[i]) >> 31) ^ 1u;
    uint32_t wd0 = 0, wd1 = 0, wd2 = 0, wd3 = 0;
    const float* base = W + (size_t)(128 * b) * NBITS + i;
    #pragma unroll
    for (int q = 0; q < 128; ++q) {
        uint32_t bit = (__float_as_uint(base[(size_t)q * NBITS]) >> 31) ^ spre;  // coalesced
        int j = q & 7, k = q >> 3;
        int a = j >> 1, hi = j & 1;
        uint32_t add = bit << (16 * hi + k);
        if (a == 0) wd0 |= add;
        else if (a == 1) wd1 |= add;
        else if (a == 2) wd2 |= add;
        else wd3 |= add;
    }
    *(uint4*)(Bt + (size_t)i * 256 + 4 * b) = make_uint4(wd0, wd1, wd2, wd3);
}

__global__ void gemv_kernel(const float* __restrict__ W, const float* __restrict__ state,
                            float* __restrict__ h0) {
    int wid = threadIdx.x >> 6, lane = threadIdx.x & 63;
    int p = blockIdx.x * 4 + wid;
    const float* row = W + (size_t)p * NBITS;
    float acc = 0.f;
    for (int k = lane; k < NBITS; k += 64) acc += row[k] * state[k];
    #pragma unroll
    for (int d = 1; d < 64; d <<= 1) acc += __shfl_xor(acc, d, 64);
    if (lane == 0) h0[p] = acc;
}

// Exact numpy-pairwise tree (mapping proven bit-exact in R1-R4, absmax 0).
__device__ __forceinline__ float tree_reduce(float x) {
    x = __uint_as_float(__builtin_amdgcn_update_dpp(__float_as_uint(x), __float_as_uint(x),
                                                    0xB1, 0xf, 0xf, false)) + x;   // quad xor1
    x = __uint_as_float(__builtin_amdgcn_update_dpp(__float_as_uint(x), __float_as_uint(x),
                                                    0x4E, 0xf, 0xf, false)) + x;   // quad xor2
    x = __uint_as_float(__builtin_amdgcn_update_dpp(__float_as_uint(x), __float_as_uint(x),
                                                    0x141, 0xf, 0xf, false)) + x;  // b^1
    x = __uint_as_float(__builtin_amdgcn_update_dpp(__float_as_uint(x), __float_as_uint(x),
                                                    0x140, 0xf, 0xf, false)) + x;  // b^2 (invariant)
#if __has_builtin(__builtin_amdgcn_permlane16_swap)
    {
        auto pr = __builtin_amdgcn_permlane16_swap(__float_as_uint(x), __float_as_uint(x),
                                                   false, false);
        x = __uint_as_float(pr[0]) + __uint_as_float(pr[1]);                        // lane^16
    }
#else
    x = __int_as_float(__builtin_amdgcn_ds_swizzle(__float_as_int(x), 0x401F)) + x;
#endif
#if __has_builtin(__builtin_amdgcn_permlane32_swap)
    {
        auto pr = __builtin_amdgcn_permlane32_swap(__float_as_uint(x), __float_as_uint(x),
                                                   false, false);
        x = __uint_as_float(pr[0]) + __uint_as_float(pr[1]);                        // lane^32
    }
#else
    x += __shfl_xor(x, 32, 64);
#endif
    return x;
}

__device__ __forceinline__ f32x2 pkmax0(f32x2 v) {
    f32x2 z = {0.0f, 0.0f};
    return __builtin_elementwise_max(v, z);
}

#define GEN_D(dst, w)                                                       \
    _Pragma("unroll")                                                       \
    for (int k = 0; k < 16; ++k) {                                          \
        u32 _lo = ((w << (31 - k)) & 0x80000000u) | 0x40000000u;            \
        u32 _hi = ((w << (15 - k)) & 0x80000000u) | 0x40000000u;            \
        dst[k] = (f32x2){__uint_as_float(_lo), __uint_as_float(_hi)};       \
    }

__launch_bounds__(256, 1)
__global__ void seq_kernel(const uint32_t* __restrict__ Bt, const float* __restrict__ h0,
                           const float* __restrict__ state, const int* __restrict__ perm,
                           float* __restrict__ out) {
    __shared__ alignas(16) float part[2][3][4];
    __shared__ alignas(16) float part0[4];
    __shared__ int2 pv[NBITS];                 // (i, bits(state[i])) in visit order

    const int t = threadIdx.x;
    const int b = t >> 2, a = t & 3;
    const int lane = t & 63, wid = t >> 6;

    for (int q = t; q < NBITS; q += 256) {
        int ii = perm[q];
        pv[q] = make_int2(ii, __float_as_int(state[ii]));
    }

    f32x2 h[16];
    #pragma unroll
    for (int k = 0; k < 16; ++k) h[k] = *(const f32x2*)(h0 + 128 * b + 2 * a + 8 * k);

    __syncthreads();

    // words for rounds 0..3 (steps 0..7); slot r&3 holds round r's pair
    u32 wA[4], wB[4];
    #pragma unroll
    for (int r = 0; r < 4; ++r) {
        wA[r] = Bt[(size_t)pv[2 * r].x * 256 + t];
        wB[r] = Bt[(size_t)pv[2 * r + 1].x * 256 + t];
    }

    f32x2 d0[2][16], d1[16];
    GEN_D(d0[0], wA[0]);           // round 0 even-step deltas
    GEN_D(d1, wB[0]);              // round 0 odd-step deltas

    float Sprev;
    {   // S(h_0), numpy-exact
        f32x2 r;
        #pragma unroll
        for (int k = 0; k < 16; ++k) {
            f32x2 x = pkmax0(h[k]);
            r = (k == 0) ? x * x : __builtin_elementwise_fma(x, x, r);
        }
        float red = tree_reduce(r.x + r.y);
        if (lane == 0) part0[wid] = red;
        asm volatile("s_waitcnt lgkmcnt(0)\n\ts_barrier" ::: "memory");
        float4 p = *(const float4*)(&part0[0]);
        Sprev = (p.x + p.y) + (p.z + p.w);
    }

    for (int rb = 0; rb < NBITS / 2; rb += 4) {
        #pragma unroll
        for (int u = 0; u < 4; ++u) {
            const int rr = rb + u;             // round = steps (2rr, 2rr+1)
            const int s  = 2 * rr;
            const int pb = rr & 1;
            const int cu = u & 1;              // current d0 buffer

            // (i, vi) for this round's decide/out — issued early, used late
            int2 pvi0 = pv[s];
            int2 pvi1 = pv[s + 1];

            // 3 candidate chains: A = h+d0, B = h+d1, C = (h+d0)+d1
            f32x2 ra, rbv, rc;
            #pragma unroll
            for (int k = 0; k < 16; ++k) {
                f32x2 va = h[k] + d0[cu][k];
                f32x2 vb = h[k] + d1[k];
                f32x2 vc = va + d1[k];         // same association as sequential ref
                f32x2 xa = pkmax0(va), xb = pkmax0(vb), xc = pkmax0(vc);
                if (k == 0) { ra = xa * xa; rbv = xb * xb; rc = xc * xc; }
                else {
                    ra  = __builtin_elementwise_fma(xa, xa, ra);
                    rbv = __builtin_elementwise_fma(xb, xb, rbv);
                    rc  = __builtin_elementwise_fma(xc, xc, rc);
                }
            }
            float Ra = tree_reduce(ra.x + ra.y);
            float Rb = tree_reduce(rbv.x + rbv.y);
            float Rc = tree_reduce(rc.x + rc.y);
            if (lane == 0) {
                part[pb][0][wid] = Ra;
                part[pb][1][wid] = Rb;
                part[pb][2][wid] = Rc;
            }
            asm volatile("s_waitcnt lgkmcnt(0)\n\ts_barrier" ::: "memory");

            // hidden under the part-read latency: next round's even deltas + loads
            GEN_D(d0[cu ^ 1], wA[(u + 1) & 3]);
            int li0 = s + 8 < NBITS ? s + 8 : NBITS - 1;
            int li1 = s + 9 < NBITS ? s + 9 : NBITS - 1;
            int iA = pv[li0].x, iB = pv[li1].x;

            float4 pa = *(const float4*)(&part[pb][0][0]);
            float4 pq = *(const float4*)(&part[pb][1][0]);
            float4 pc = *(const float4*)(&part[pb][2][0]);

            wA[u] = Bt[(size_t)iA * 256 + t];  // round rr+4's words (4-round slack)
            wB[u] = Bt[(size_t)iB * 256 + t];

            float Sa = (pa.x + pa.y) + (pa.z + pa.w);
            float Sb = (pq.x + pq.y) + (pq.z + pq.w);
            float Sc = (pc.x + pc.y) + (pc.z + pc.w);

            // accept iff E_new < E_prev  <=>  S_new > S_prev (ties reject)
            bool acc0 = Sa > Sprev;
            bool acc1 = acc0 ? (Sc > Sa) : (Sb > Sprev);
            Sprev = acc1 ? (acc0 ? Sc : Sb) : (acc0 ? Sa : Sprev);

            if (t == 0) {
                float v0 = __int_as_float(pvi0.y), v1 = __int_as_float(pvi1.y);
                out[pvi0.x] = acc0 ? -v0 : v0;
                out[pvi1.x] = acc1 ? -v1 : v1;
            }

            float f0s = acc0 ? 1.0f : 0.0f, f1s = acc1 ? 1.0f : 0.0f;
            f32x2 f0 = {f0s, f0s}, f1 = {f1s, f1s};
            #pragma unroll
            for (int k = 0; k < 16; ++k) {     // exact: d*1=d, d*0=+/-0, +0 adds are exact
                f32x2 hh = __builtin_elementwise_fma(d0[cu][k], f0, h[k]);
                h[k] = __builtin_elementwise_fma(d1[k], f1, hh);
            }

            // next round's odd deltas (d1 single-buffered; last use was the update above)
            GEN_D(d1, wB[(u + 1) & 3]);
        }
    }
}

extern "C" void kernel_launch(void* const* d_in, const int* in_sizes, int n_in,
                              void* d_out, int out_size, void* d_ws, size_t ws_size,
                              hipStream_t stream) {
    const float* W     = (const float*)d_in[0];
    const float* state = (const float*)d_in[1];
    const int*   perm  = (const int*)d_in[2];
    float*       out   = (float*)d_out;

    uint32_t* Bt = (uint32_t*)d_ws;
    float*    h0 = (float*)((char*)d_ws + (size_t)4096 * 256 * 4);

    pack_kernel<<<1024, 256, 0, stream>>>(W, state, Bt);
    gemv_kernel<<<2048, 256, 0, stream>>>(W, state, h0);
    seq_kernel<<<1, 256, 0, stream>>>(Bt, h0, state, perm, out);
}